// Round 5
// baseline (295.073 us; speedup 1.0000x reference)
//
#include <hip/hip_runtime.h>
#include <math.h>

#define BNUM 16
#define HNUM 512
#define WNUM 512
#define HW (HNUM*WNUM)            // 262144
#define NPLANE (BNUM*HW)          // 4194304
#define RR 8
#define KWIN 17
#define EPSF 1e-5f
#define THRESHF 0.8f
#define STRIP 128
#define SEG 64
#define INV_KK (1.0f/289.0f)
#define INV_NUMEL (1.0f/12582912.0f)

// ---------------- Kernel 1: per-pixel prep ----------------
// Reads input (3ch) + output (3ch), writes guide I, initial mask p, abs-diff sum s.
__global__ __launch_bounds__(256) void prep_kernel(
        const float* __restrict__ outp, const float* __restrict__ inp,
        float* __restrict__ PI, float* __restrict__ PP, float* __restrict__ PS) {
    int pix = (blockIdx.x * 256 + threadIdx.x) * 4;
    if (pix >= NPLANE) return;
    int b = pix >> 18;            // / HW
    int r = pix & (HW - 1);
    size_t base = (size_t)b * 3 * HW + r;

    float4 a0 = *(const float4*)(inp + base);
    float4 a1 = *(const float4*)(inp + base + HW);
    float4 a2 = *(const float4*)(inp + base + 2 * HW);
    float4 b0 = *(const float4*)(outp + base);
    float4 b1 = *(const float4*)(outp + base + HW);
    float4 b2 = *(const float4*)(outp + base + 2 * HW);

    float4 I4, P4, S4;
#define DOCOMP(M) { \
    float i0 = (a0.M + 1.f) * 0.5f; \
    float i1 = (a1.M + 1.f) * 0.5f; \
    float i2 = (a2.M + 1.f) * 0.5f; \
    I4.M = (i0 + i1 + i2) * (1.f/3.f); \
    float mx = fmaxf(i0, fmaxf(i1, i2)); \
    P4.M = (mx > THRESHF) ? 1.f : 0.f; \
    S4.M = 0.5f * (fabsf(b0.M - a0.M) + fabsf(b1.M - a1.M) + fabsf(b2.M - a2.M)); \
}
    DOCOMP(x) DOCOMP(y) DOCOMP(z) DOCOMP(w)
#undef DOCOMP

    size_t po = (size_t)b * HW + r;
    *(float4*)(PI + po) = I4;
    *(float4*)(PP + po) = P4;
    *(float4*)(PS + po) = S4;
}

// ---------------- Kernel 2: box(I), box(p), box(I*p), box(I*I) -> a, b ----------------
// Streaming separable box: horizontal 17-tap from LDS row, vertical sliding sum with
// a 17-entry ring of h-rows in LDS (per-thread column, no cross-thread sharing).
__global__ __launch_bounds__(STRIP) void boxc_ab(
        const float* __restrict__ PI, const float* __restrict__ PP,
        float* __restrict__ PA, float* __restrict__ PB) {
    __shared__ float rowI[STRIP + 2 * RR];
    __shared__ float rowP[STRIP + 2 * RR];
    __shared__ float ring[4][KWIN][STRIP];

    int t  = threadIdx.x;
    int x0 = blockIdx.x * STRIP;
    int ys = blockIdx.y * SEG;
    int b  = blockIdx.z;

    const float* Ib = PI + (size_t)b * HW;
    const float* Pb = PP + (size_t)b * HW;
    float* Ab = PA + (size_t)b * HW;
    float* Bb = PB + (size_t)b * HW;

    // zero ring (each thread zeroes exactly its own columns: i % STRIP == t)
    for (int i = t; i < 4 * KWIN * STRIP; i += STRIP) (&ring[0][0][0])[i] = 0.f;

    float vI = 0.f, vP = 0.f, vIp = 0.f, vII = 0.f;
    int slot = 0;
    __syncthreads();

    for (int yin = ys - RR; yin <= ys + SEG - 1 + RR; ++yin) {
        bool rowvalid = (yin >= 0) && (yin < HNUM);
        for (int i = t; i < STRIP + 2 * RR; i += STRIP) {
            int x = x0 - RR + i;
            float vi = 0.f, vp = 0.f;
            if (rowvalid && x >= 0 && x < WNUM) {
                size_t off = (size_t)yin * WNUM + x;
                vi = Ib[off];
                vp = Pb[off];
            }
            rowI[i] = vi;
            rowP[i] = vp;
        }
        __syncthreads();

        float sI = 0.f, sP = 0.f, sIp = 0.f, sII = 0.f;
#pragma unroll
        for (int d = 0; d < KWIN; ++d) {
            float iv = rowI[t + d];
            float pv = rowP[t + d];
            sI  += iv;
            sP  += pv;
            sIp += iv * pv;
            sII += iv * iv;
        }

        vI  += sI  - ring[0][slot][t]; ring[0][slot][t] = sI;
        vP  += sP  - ring[1][slot][t]; ring[1][slot][t] = sP;
        vIp += sIp - ring[2][slot][t]; ring[2][slot][t] = sIp;
        vII += sII - ring[3][slot][t]; ring[3][slot][t] = sII;
        slot = (slot + 1 == KWIN) ? 0 : slot + 1;

        int yout = yin - RR;
        if (yout >= ys) {
            float mI  = vI  * INV_KK;
            float mP  = vP  * INV_KK;
            float mIp = vIp * INV_KK;
            float mII = vII * INV_KK;
            float cov = mIp - mI * mP;
            float var = mII - mI * mI;
            float a   = cov / (var + EPSF);
            float bb  = mP - a * mI;
            size_t off = (size_t)yout * WNUM + x0 + t;
            Ab[off] = a;
            Bb[off] = bb;
        }
        __syncthreads();
    }
}

// ---------------- Kernel 3: box(a), box(b) -> mask -> loss ----------------
__global__ __launch_bounds__(STRIP) void boxc_mask_loss(
        const float* __restrict__ PA, const float* __restrict__ PB,
        const float* __restrict__ PI, const float* __restrict__ PS,
        float* __restrict__ loss_out) {
    __shared__ float rowA[STRIP + 2 * RR];
    __shared__ float rowB[STRIP + 2 * RR];
    __shared__ float ring[2][KWIN][STRIP];
    __shared__ float red[2];

    int t  = threadIdx.x;
    int x0 = blockIdx.x * STRIP;
    int ys = blockIdx.y * SEG;
    int b  = blockIdx.z;

    const float* Ab = PA + (size_t)b * HW;
    const float* Bb = PB + (size_t)b * HW;
    const float* Ib = PI + (size_t)b * HW;
    const float* Sb = PS + (size_t)b * HW;

    for (int i = t; i < 2 * KWIN * STRIP; i += STRIP) (&ring[0][0][0])[i] = 0.f;

    float vA = 0.f, vB = 0.f;
    int slot = 0;
    float partial = 0.f;
    __syncthreads();

    for (int yin = ys - RR; yin <= ys + SEG - 1 + RR; ++yin) {
        bool rowvalid = (yin >= 0) && (yin < HNUM);
        for (int i = t; i < STRIP + 2 * RR; i += STRIP) {
            int x = x0 - RR + i;
            float va = 0.f, vb = 0.f;
            if (rowvalid && x >= 0 && x < WNUM) {
                size_t off = (size_t)yin * WNUM + x;
                va = Ab[off];
                vb = Bb[off];
            }
            rowA[i] = va;
            rowB[i] = vb;
        }
        __syncthreads();

        float sA = 0.f, sB = 0.f;
#pragma unroll
        for (int d = 0; d < KWIN; ++d) {
            sA += rowA[t + d];
            sB += rowB[t + d];
        }

        vA += sA - ring[0][slot][t]; ring[0][slot][t] = sA;
        vB += sB - ring[1][slot][t]; ring[1][slot][t] = sB;
        slot = (slot + 1 == KWIN) ? 0 : slot + 1;

        int yout = yin - RR;
        if (yout >= ys) {
            float mA = vA * INV_KK;
            float mB = vB * INV_KK;
            size_t off = (size_t)yout * WNUM + x0 + t;
            float refined = mA * Ib[off] + mB;
            float mask = fminf(fmaxf(refined, 0.f), 1.f);
            partial += mask * Sb[off];
        }
        __syncthreads();
    }

    // block reduction: 2 waves of 64
#pragma unroll
    for (int off = 32; off > 0; off >>= 1)
        partial += __shfl_down(partial, off);
    if ((t & 63) == 0) red[t >> 6] = partial;
    __syncthreads();
    if (t == 0) atomicAdd(loss_out, (red[0] + red[1]) * INV_NUMEL);
}

extern "C" void kernel_launch(void* const* d_in, const int* in_sizes, int n_in,
                              void* d_out, int out_size, void* d_ws, size_t ws_size,
                              hipStream_t stream) {
    // setup_inputs order: "output" first, then "input"
    const float* outp = (const float*)d_in[0];
    const float* inp  = (const float*)d_in[1];

    float* ws = (float*)d_ws;
    float* PI = ws;
    float* PP = ws + (size_t)NPLANE;
    float* PS = ws + (size_t)2 * NPLANE;
    float* PA = ws + (size_t)3 * NPLANE;
    float* PB = ws + (size_t)4 * NPLANE;

    hipMemsetAsync(d_out, 0, sizeof(float), stream);

    prep_kernel<<<NPLANE / (256 * 4), 256, 0, stream>>>(outp, inp, PI, PP, PS);

    dim3 grid(WNUM / STRIP, HNUM / SEG, BNUM);
    boxc_ab<<<grid, STRIP, 0, stream>>>(PI, PP, PA, PB);
    boxc_mask_loss<<<grid, STRIP, 0, stream>>>(PA, PB, PI, PS, (float*)d_out);
}

// Round 7
// 211.773 us; speedup vs baseline: 1.3933x; 1.3933x over previous
//
#include <hip/hip_runtime.h>
#include <math.h>

#define BNUM 16
#define HNUM 512
#define WNUM 512
#define HW (HNUM*WNUM)            // 262144
#define NPLANE (BNUM*HW)          // 4194304
#define RR 8
#define KWIN 17
#define EPSF 1e-5f
#define THRESHF 0.8f
#define STRIP 128
#define SEG_AB 32                 // boxc_ab: 39KB LDS -> 4 blocks/CU, grid exactly fills
#define SEG_ML 16                 // boxc_mask_loss: 20KB LDS -> 8 blocks/CU
#define INV_KK (1.0f/289.0f)
#define INV_NUMEL (1.0f/12582912.0f)

// ---------------- Kernel 1: per-pixel prep ----------------
__global__ __launch_bounds__(256) void prep_kernel(
        const float* __restrict__ outp, const float* __restrict__ inp,
        float* __restrict__ PI, float* __restrict__ PP, float* __restrict__ PS) {
    int pix = (blockIdx.x * 256 + threadIdx.x) * 4;
    if (pix >= NPLANE) return;
    int b = pix >> 18;
    int r = pix & (HW - 1);
    size_t base = (size_t)b * 3 * HW + r;

    float4 a0 = *(const float4*)(inp + base);
    float4 a1 = *(const float4*)(inp + base + HW);
    float4 a2 = *(const float4*)(inp + base + 2 * HW);
    float4 b0 = *(const float4*)(outp + base);
    float4 b1 = *(const float4*)(outp + base + HW);
    float4 b2 = *(const float4*)(outp + base + 2 * HW);

    float4 I4, P4, S4;
#define DOCOMP(M) { \
    float i0 = (a0.M + 1.f) * 0.5f; \
    float i1 = (a1.M + 1.f) * 0.5f; \
    float i2 = (a2.M + 1.f) * 0.5f; \
    I4.M = (i0 + i1 + i2) * (1.f/3.f); \
    float mx = fmaxf(i0, fmaxf(i1, i2)); \
    P4.M = (mx > THRESHF) ? 1.f : 0.f; \
    S4.M = 0.5f * (fabsf(b0.M - a0.M) + fabsf(b1.M - a1.M) + fabsf(b2.M - a2.M)); \
}
    DOCOMP(x) DOCOMP(y) DOCOMP(z) DOCOMP(w)
#undef DOCOMP

    size_t po = (size_t)b * HW + r;
    *(float4*)(PI + po) = I4;
    *(float4*)(PP + po) = P4;
    *(float4*)(PS + po) = S4;
}

// ---------------- Kernel 2: box(I), box(p), box(I*p), box(I*I) -> a, b ----------------
// Streaming separable box. One barrier per row: double-buffered row LDS + register
// prefetch of the NEXT row issued before the barrier (latency hides under compute).
// Ring of 17 horizontal sums is per-thread-column private (no sync needed).
__global__ __launch_bounds__(STRIP) void boxc_ab(
        const float* __restrict__ PI, const float* __restrict__ PP,
        float* __restrict__ PA, float* __restrict__ PB) {
    __shared__ float rowI[2][STRIP + 2 * RR];
    __shared__ float rowP[2][STRIP + 2 * RR];
    __shared__ float ring[4][KWIN][STRIP];

    int t  = threadIdx.x;
    int x0 = blockIdx.x * STRIP;
    int ys = blockIdx.y * SEG_AB;
    int b  = blockIdx.z;

    const float* Ib = PI + (size_t)b * HW;
    const float* Pb = PP + (size_t)b * HW;
    float* Ab = PA + (size_t)b * HW;
    float* Bb = PB + (size_t)b * HW;

    // zero ring: each thread touches only its own column slots -> no barrier needed
    for (int i = t; i < 4 * KWIN * STRIP; i += STRIP) (&ring[0][0][0])[i] = 0.f;

    int xg  = x0 - RR + t;
    bool xok  = (xg >= 0) && (xg < WNUM);
    int xg2 = x0 - RR + STRIP + t;
    bool x2ok = (t < 2 * RR) && (xg2 < WNUM);

    float vI = 0.f, vP = 0.f, vIp = 0.f, vII = 0.f;
    int slot = 0;

    // prefetch first row into registers
    float ri0 = 0.f, rp0 = 0.f, ri1 = 0.f, rp1 = 0.f;
    {
        int y = ys - RR;
        if (y >= 0 && y < HNUM) {
            size_t ro = (size_t)y * WNUM;
            if (xok)  { ri0 = Ib[ro + xg];  rp0 = Pb[ro + xg]; }
            if (x2ok) { ri1 = Ib[ro + xg2]; rp1 = Pb[ro + xg2]; }
        }
    }

    int cur = 0;
    for (int k = 0; k < SEG_AB + 2 * RR; ++k) {
        int yin = ys - RR + k;
        // publish prefetched row to LDS buffer `cur`
        rowI[cur][t] = ri0;
        rowP[cur][t] = rp0;
        if (t < 2 * RR) { rowI[cur][STRIP + t] = ri1; rowP[cur][STRIP + t] = rp1; }

        // issue next row's loads NOW (consumed after this iteration's compute)
        ri0 = 0.f; rp0 = 0.f; ri1 = 0.f; rp1 = 0.f;
        int yn = yin + 1;
        if (k + 1 < SEG_AB + 2 * RR && yn >= 0 && yn < HNUM) {
            size_t ro = (size_t)yn * WNUM;
            if (xok)  { ri0 = Ib[ro + xg];  rp0 = Pb[ro + xg]; }
            if (x2ok) { ri1 = Ib[ro + xg2]; rp1 = Pb[ro + xg2]; }
        }

        __syncthreads();   // rowI/rowP[cur] visible to all

        float sI = 0.f, sP = 0.f, sIp = 0.f, sII = 0.f;
#pragma unroll
        for (int d = 0; d < KWIN; ++d) {
            float iv = rowI[cur][t + d];
            float pv = rowP[cur][t + d];
            sI  += iv;
            sP  += pv;
            sIp += iv * pv;
            sII += iv * iv;
        }

        vI  += sI  - ring[0][slot][t]; ring[0][slot][t] = sI;
        vP  += sP  - ring[1][slot][t]; ring[1][slot][t] = sP;
        vIp += sIp - ring[2][slot][t]; ring[2][slot][t] = sIp;
        vII += sII - ring[3][slot][t]; ring[3][slot][t] = sII;
        slot = (slot + 1 == KWIN) ? 0 : slot + 1;

        int yout = yin - RR;
        if (yout >= ys) {
            float mI  = vI  * INV_KK;
            float mP  = vP  * INV_KK;
            float mIp = vIp * INV_KK;
            float mII = vII * INV_KK;
            float cov = mIp - mI * mP;
            float var = mII - mI * mI;
            float a   = cov / (var + EPSF);
            float bb  = mP - a * mI;
            size_t off = (size_t)yout * WNUM + x0 + t;
            Ab[off] = a;
            Bb[off] = bb;
        }
        cur ^= 1;   // next write goes to other buffer; this iter's reads already done by B_{k+1}
    }
}

// ---------------- Kernel 3: box(a), box(b) -> mask -> loss ----------------
__global__ __launch_bounds__(STRIP) void boxc_mask_loss(
        const float* __restrict__ PA, const float* __restrict__ PB,
        const float* __restrict__ PI, const float* __restrict__ PS,
        float* __restrict__ loss_out) {
    __shared__ float rowA[2][STRIP + 2 * RR];
    __shared__ float rowB[2][STRIP + 2 * RR];
    __shared__ float ring[2][KWIN][STRIP];
    __shared__ float red[2];

    int t  = threadIdx.x;
    int x0 = blockIdx.x * STRIP;
    int ys = blockIdx.y * SEG_ML;
    int b  = blockIdx.z;

    const float* Ab = PA + (size_t)b * HW;
    const float* Bb = PB + (size_t)b * HW;
    const float* Ib = PI + (size_t)b * HW;
    const float* Sb = PS + (size_t)b * HW;

    for (int i = t; i < 2 * KWIN * STRIP; i += STRIP) (&ring[0][0][0])[i] = 0.f;

    int xg  = x0 - RR + t;
    bool xok  = (xg >= 0) && (xg < WNUM);
    int xg2 = x0 - RR + STRIP + t;
    bool x2ok = (t < 2 * RR) && (xg2 < WNUM);

    float vA = 0.f, vB = 0.f;
    int slot = 0;
    float partial = 0.f;

    float ra0 = 0.f, rb0 = 0.f, ra1 = 0.f, rb1 = 0.f;
    {
        int y = ys - RR;
        if (y >= 0 && y < HNUM) {
            size_t ro = (size_t)y * WNUM;
            if (xok)  { ra0 = Ab[ro + xg];  rb0 = Bb[ro + xg]; }
            if (x2ok) { ra1 = Ab[ro + xg2]; rb1 = Bb[ro + xg2]; }
        }
    }

    int cur = 0;
    for (int k = 0; k < SEG_ML + 2 * RR; ++k) {
        int yin = ys - RR + k;
        rowA[cur][t] = ra0;
        rowB[cur][t] = rb0;
        if (t < 2 * RR) { rowA[cur][STRIP + t] = ra1; rowB[cur][STRIP + t] = rb1; }

        ra0 = 0.f; rb0 = 0.f; ra1 = 0.f; rb1 = 0.f;
        int yn = yin + 1;
        if (k + 1 < SEG_ML + 2 * RR && yn >= 0 && yn < HNUM) {
            size_t ro = (size_t)yn * WNUM;
            if (xok)  { ra0 = Ab[ro + xg];  rb0 = Bb[ro + xg]; }
            if (x2ok) { ra1 = Ab[ro + xg2]; rb1 = Bb[ro + xg2]; }
        }

        __syncthreads();

        float sA = 0.f, sB = 0.f;
#pragma unroll
        for (int d = 0; d < KWIN; ++d) {
            sA += rowA[cur][t + d];
            sB += rowB[cur][t + d];
        }

        vA += sA - ring[0][slot][t]; ring[0][slot][t] = sA;
        vB += sB - ring[1][slot][t]; ring[1][slot][t] = sB;
        slot = (slot + 1 == KWIN) ? 0 : slot + 1;

        int yout = yin - RR;
        if (yout >= ys) {
            float mA = vA * INV_KK;
            float mB = vB * INV_KK;
            size_t off = (size_t)yout * WNUM + x0 + t;
            float refined = mA * Ib[off] + mB;
            float mask = fminf(fmaxf(refined, 0.f), 1.f);
            partial += mask * Sb[off];
        }
        cur ^= 1;
    }

    // block reduction: 2 waves of 64
#pragma unroll
    for (int off = 32; off > 0; off >>= 1)
        partial += __shfl_down(partial, off);
    if ((t & 63) == 0) red[t >> 6] = partial;
    __syncthreads();
    if (t == 0) atomicAdd(loss_out, (red[0] + red[1]) * INV_NUMEL);
}

extern "C" void kernel_launch(void* const* d_in, const int* in_sizes, int n_in,
                              void* d_out, int out_size, void* d_ws, size_t ws_size,
                              hipStream_t stream) {
    const float* outp = (const float*)d_in[0];
    const float* inp  = (const float*)d_in[1];

    float* ws = (float*)d_ws;
    float* PI = ws;
    float* PP = ws + (size_t)NPLANE;
    float* PS = ws + (size_t)2 * NPLANE;
    float* PA = ws + (size_t)3 * NPLANE;
    float* PB = ws + (size_t)4 * NPLANE;

    hipMemsetAsync(d_out, 0, sizeof(float), stream);

    prep_kernel<<<NPLANE / (256 * 4), 256, 0, stream>>>(outp, inp, PI, PP, PS);

    dim3 grid_ab(WNUM / STRIP, HNUM / SEG_AB, BNUM);
    boxc_ab<<<grid_ab, STRIP, 0, stream>>>(PI, PP, PA, PB);

    dim3 grid_ml(WNUM / STRIP, HNUM / SEG_ML, BNUM);
    boxc_mask_loss<<<grid_ml, STRIP, 0, stream>>>(PA, PB, PI, PS, (float*)d_out);
}